// Round 7
// baseline (218.206 us; speedup 1.0000x reference)
//
#include <hip/hip_runtime.h>

// Problem constants
#define B_    4
#define S_    2048
#define HID_  1024
#define NO_   1024     // NH*HD
#define EPS_  1e-6f
#define M1_   (B_ * S_)   // 8192

typedef __attribute__((ext_vector_type(8))) short  short8;
typedef __attribute__((ext_vector_type(4))) float  f32x4;
typedef unsigned short ushort_t;

__device__ __forceinline__ unsigned short f2bf(float f) {
  union { float f; unsigned int u; } v; v.f = f;
  unsigned int r = v.u + 0x7FFFu + ((v.u >> 16) & 1u);  // RNE
  return (unsigned short)(r >> 16);
}
__device__ __forceinline__ unsigned pack2(float a, float b) {
  return (unsigned)f2bf(a) | ((unsigned)f2bf(b) << 16);
}

// async global->LDS, 16B per lane, dest = wave-uniform base + lane*16
typedef __attribute__((address_space(1))) const void GASV;
typedef __attribute__((address_space(3))) void LASV;
__device__ __forceinline__ void gld16(const void* g, void* l) {
  __builtin_amdgcn_global_load_lds((GASV*)g, (LASV*)l, 16, 0, 0);
}

// ---------------------------------------------------------------------------
// Prep stage 1: WvT transpose+cvt (ids 0..1023) | Hb = bf16(H) (ids 1024..9215)
// (Ab prep moved into the k_vt launch so it overlaps GEMM1.)
// ---------------------------------------------------------------------------
__global__ __launch_bounds__(256) void k_prep0(
    const float* __restrict__ Wv, ushort_t* __restrict__ WvT,
    const float* __restrict__ H,  ushort_t* __restrict__ Hb) {
  int id = blockIdx.x;
  if (id < 1024) {
    __shared__ float tile[32][33];
    int k0 = (id & 31) * 32;
    int n0 = (id >> 5) * 32;
    int tx = threadIdx.x & 31, ty = threadIdx.x >> 5;   // 32 x 8
    for (int i = ty; i < 32; i += 8)
      tile[i][tx] = Wv[(size_t)(k0 + i) * NO_ + n0 + tx];
    __syncthreads();
    for (int i = ty; i < 32; i += 8)
      WvT[(size_t)(n0 + i) * HID_ + k0 + tx] = f2bf(tile[tx][i]);
  } else {
    size_t i = ((size_t)(id - 1024) * 256 + threadIdx.x) * 4;
    float4 v = *(const float4*)(H + i);
    uint2 p; p.x = pack2(v.x, v.y); p.y = pack2(v.z, v.w);
    *(uint2*)(Hb + i) = p;
  }
}

// ---------------------------------------------------------------------------
// Merged launch: GEMM1 (ids 0..511) + Ab prep (ids 512..2559).
// GEMM1: Vt[b][n][s] = bf16( sum_k WvT[n][k]*Hb[m][k] + bv[n] ), m=b*S+s.
//   128n x 128m tile, 4 waves (64x64 each), BK=32, 3x16KB ring (48 KB ->
//   2 GEMM blocks + 1 prep block per CU), r6 phase schedule, vmcnt 4/4/0.
//   XCD decode (r6-verified): per-XCD Hb m-band (2MB) + WvT (2MB) L2-resident.
// Ab prep: one wave per row, causal mask + rowsum-normalize + cvt (r0 body).
//   Streams 100 MB of HBM under the GEMM compute on the 3rd CU slot.
// ---------------------------------------------------------------------------
__global__ __launch_bounds__(256, 3) void k_vtA(
    const ushort_t* __restrict__ WvT, const ushort_t* __restrict__ Hb,
    const float* __restrict__ bv, ushort_t* __restrict__ Vt,
    const float* __restrict__ A, ushort_t* __restrict__ Ab) {
  __shared__ __align__(16) char lds[3 * 16384];   // per buf: A 8KB @0, B 8KB @8192
  int id = blockIdx.x;
  if (id < 512) {
    int xcd = id & 7;
    int mem = id >> 3;                       // 0..63
    int n0  = (mem & 7) * 128;
    int m0  = (xcd * 8 + (mem >> 3)) * 128;  // per-XCD contiguous m-band
    int tid = threadIdx.x;
    int wave = tid >> 6, lane = tid & 63;
    int lq = lane >> 4, lm = lane & 15;
    int wq = wave >> 1, wm = wave & 1;       // wave tile: 64n x 64m

    int rr = lane >> 2;
    int sc = (lane & 3) ^ ((rr >> 1) & 3);
    int fo = (lq ^ ((lm >> 1) & 3)) << 4;
    const ushort_t* pa = WvT + (size_t)(n0 + wave * 32 + rr) * HID_ + sc * 8;
    const ushort_t* pb = Hb  + (size_t)(m0 + wave * 32 + rr) * HID_ + sc * 8;

    f32x4 acc[4][4];
    for (int i = 0; i < 4; i++) for (int j = 0; j < 4; j++) acc[i][j] = (f32x4)0.0f;

    const int N = 32;   // K-steps of 32
    // prologue: full stage of tiles 0,1 (4 gld16 each per wave)
#pragma unroll
    for (int tpre = 0; tpre < 2; ++tpre) {
      char* wb = lds + tpre * 16384;
      gld16(pa,             wb + wave * 2048);
      gld16(pa + 16 * HID_, wb + wave * 2048 + 1024);
      gld16(pb,             wb + 8192 + wave * 2048);
      gld16(pb + 16 * HID_, wb + 8192 + wave * 2048 + 1024);
      pa += 32; pb += 32;
    }
    asm volatile("s_waitcnt vmcnt(4)" ::: "memory");
    __builtin_amdgcn_s_barrier();

    int rbuf = 0;
    for (int it = 0; it < N; ++it) {
      int wbuf = rbuf + 2; if (wbuf >= 3) wbuf -= 3;
      bool stg = (it + 2) < N;
      const char* ra = lds + rbuf * 16384;
      char* wb = lds + wbuf * 16384;
      short8 af[4], bf0, bf1;
      // ---- phase 0: n-frags 0,1
#pragma unroll
      for (int mi = 0; mi < 4; mi++)
        af[mi] = *(const short8*)(ra + (wq * 64 + mi * 16 + lm) * 64 + fo);
      bf0 = *(const short8*)(ra + 8192 + (wm * 64 +  0 + lm) * 64 + fo);
      bf1 = *(const short8*)(ra + 8192 + (wm * 64 + 16 + lm) * 64 + fo);
      if (stg) { gld16(pb, wb + 8192 + wave * 2048); gld16(pb + 16 * HID_, wb + 8192 + wave * 2048 + 1024); }
      __builtin_amdgcn_s_barrier();
      __builtin_amdgcn_s_setprio(1);
#pragma unroll
      for (int mi = 0; mi < 4; mi++) {
        acc[mi][0] = __builtin_amdgcn_mfma_f32_16x16x32_bf16(af[mi], bf0, acc[mi][0], 0, 0, 0);
        acc[mi][1] = __builtin_amdgcn_mfma_f32_16x16x32_bf16(af[mi], bf1, acc[mi][1], 0, 0, 0);
      }
      __builtin_amdgcn_s_setprio(0);
      __builtin_amdgcn_s_barrier();
      // ---- phase 1: n-frags 2,3
      bf0 = *(const short8*)(ra + 8192 + (wm * 64 + 32 + lm) * 64 + fo);
      bf1 = *(const short8*)(ra + 8192 + (wm * 64 + 48 + lm) * 64 + fo);
      if (stg) { gld16(pa, wb + wave * 2048); gld16(pa + 16 * HID_, wb + wave * 2048 + 1024); pa += 32; pb += 32; }
      __builtin_amdgcn_s_barrier();
      __builtin_amdgcn_s_setprio(1);
#pragma unroll
      for (int mi = 0; mi < 4; mi++) {
        acc[mi][2] = __builtin_amdgcn_mfma_f32_16x16x32_bf16(af[mi], bf0, acc[mi][2], 0, 0, 0);
        acc[mi][3] = __builtin_amdgcn_mfma_f32_16x16x32_bf16(af[mi], bf1, acc[mi][3], 0, 0, 0);
      }
      __builtin_amdgcn_s_setprio(0);
      if (it < N - 1) {
        if (it + 2 < N) asm volatile("s_waitcnt vmcnt(4)" ::: "memory");
        else            asm volatile("s_waitcnt vmcnt(0)" ::: "memory");
      }
      __builtin_amdgcn_s_barrier();
      rbuf = (rbuf == 2) ? 0 : rbuf + 1;
    }
    for (int mi = 0; mi < 4; mi++) {
      for (int r = 0; r < 4; r++) {
        int n = n0 + wq * 64 + mi * 16 + lq * 4 + r;
        float bias = bv[n];
        for (int ni = 0; ni < 4; ni++) {
          int m = m0 + wm * 64 + ni * 16 + lm;
          int b = m >> 11;
          int s = m & 2047;
          Vt[((size_t)b * NO_ + n) * S_ + s] = f2bf(acc[mi][ni][r] + bias);
        }
      }
    }
  } else {
    // Ab prep: row in VGPRs, causal mask, rowsum, scale, cvt (r0-verified body)
    int row  = (id - 512) * 4 + (threadIdx.x >> 6);   // row = b*S + q
    int lane = threadIdx.x & 63;
    int q = row & 2047;
    int wend = ((q >> 7) + 1) << 7;
    const float* rp = A + (size_t)row * S_;
    float4 v[8];
    float s = 0.f;
#pragma unroll
    for (int i = 0; i < 8; i++) {
      int k = i * 256 + lane * 4;
      if (k < wend) {
        float4 t = *(const float4*)(rp + k);
        t.x = (k + 0 <= q) ? t.x : 0.f;
        t.y = (k + 1 <= q) ? t.y : 0.f;
        t.z = (k + 2 <= q) ? t.z : 0.f;
        t.w = (k + 3 <= q) ? t.w : 0.f;
        v[i] = t;
        s += t.x + t.y + t.z + t.w;
      }
    }
    for (int off = 1; off < 64; off <<= 1) s += __shfl_xor(s, off, 64);
    float inv = 1.0f / (EPS_ + s);
    ushort_t* op = Ab + (size_t)row * S_;
#pragma unroll
    for (int i = 0; i < 8; i++) {
      int k = i * 256 + lane * 4;
      if (k < wend) {
        uint2 p;
        p.x = pack2(v[i].x * inv, v[i].y * inv);
        p.y = pack2(v[i].z * inv, v[i].w * inv);
        *(uint2*)(op + k) = p;
      }
    }
  }
}

// ---------------------------------------------------------------------------
// GEMM 2: out[b,q,n] = sum_k Ab[b,q,k] * Vt[b,n,k]   (inv pre-applied in Ab)
// 128q x 128n tile, 4 waves (64x64 each), BK=32, 3x16KB ring (48 KB ->
// 2 blocks/CU), r6 phase schedule, vmcnt 4/4/0. 512 blocks: ids c and c+256
// land on the same CU (round-robin) and get t = 15-g / g -> complementary
// causal depths, exactly 68 K-steps per CU; heavy round dispatches first.
// xcd = n-tile index -> each XCD's Vt panel set (2 MB) is L2-resident.
// ---------------------------------------------------------------------------
__global__ __launch_bounds__(256, 2) void k_attn(
    const ushort_t* __restrict__ Ab, const ushort_t* __restrict__ Vt,
    float* __restrict__ out) {
  __shared__ __align__(16) char lds[3 * 16384];   // per buf: A 8KB @0, B 8KB @8192
  int id  = blockIdx.x;
  int c   = id & 255;
  int rnd = id >> 8;                      // 0 = heavy round
  int col = c & 31;                       // (n-tile, b)
  int g   = c >> 5;                       // 0..7
  int t   = rnd ? g : (15 - g);
  int n0  = (col & 7) * 128;
  int b   = col >> 3;
  int q0  = t * 128;
  int tid = threadIdx.x;
  int wave = tid >> 6, lane = tid & 63;
  int lq = lane >> 4, lm = lane & 15;
  int wq = wave >> 1, wn = wave & 1;      // wave tile: 64q x 64n

  int rr = lane >> 2;
  int sc = (lane & 3) ^ ((rr >> 1) & 3);
  int fo = (lq ^ ((lm >> 1) & 3)) << 4;
  const ushort_t* pa = Ab + (size_t)(b * S_ + q0 + wave * 32 + rr) * S_ + sc * 8;
  const ushort_t* pb = Vt + (size_t)(b * NO_ + n0 + wave * 32 + rr) * S_ + sc * 8;

  f32x4 acc[4][4];
  for (int i = 0; i < 4; i++) for (int j = 0; j < 4; j++) acc[i][j] = (f32x4)0.0f;

  const int N = 4 * t + 4;   // K = 128*(t+1), BK=32; min 4 >= 2
  // prologue: full stage of tiles 0,1 (4 gld16 each per wave)
#pragma unroll
  for (int tpre = 0; tpre < 2; ++tpre) {
    char* wb = lds + tpre * 16384;
    gld16(pa,           wb + wave * 2048);
    gld16(pa + 16 * S_, wb + wave * 2048 + 1024);
    gld16(pb,           wb + 8192 + wave * 2048);
    gld16(pb + 16 * S_, wb + 8192 + wave * 2048 + 1024);
    pa += 32; pb += 32;
  }
  asm volatile("s_waitcnt vmcnt(4)" ::: "memory");
  __builtin_amdgcn_s_barrier();

  int rbuf = 0;
  for (int it = 0; it < N; ++it) {
    int wbuf = rbuf + 2; if (wbuf >= 3) wbuf -= 3;
    bool stg = (it + 2) < N;
    const char* ra = lds + rbuf * 16384;
    char* wb = lds + wbuf * 16384;
    short8 af[4], bf0, bf1;
    // ---- phase 0: n-frags 0,1
#pragma unroll
    for (int mi = 0; mi < 4; mi++)
      af[mi] = *(const short8*)(ra + (wq * 64 + mi * 16 + lm) * 64 + fo);
    bf0 = *(const short8*)(ra + 8192 + (wn * 64 +  0 + lm) * 64 + fo);
    bf1 = *(const short8*)(ra + 8192 + (wn * 64 + 16 + lm) * 64 + fo);
    if (stg) { gld16(pb, wb + 8192 + wave * 2048); gld16(pb + 16 * S_, wb + 8192 + wave * 2048 + 1024); }
    __builtin_amdgcn_s_barrier();
    __builtin_amdgcn_s_setprio(1);
#pragma unroll
    for (int mi = 0; mi < 4; mi++) {
      acc[mi][0] = __builtin_amdgcn_mfma_f32_16x16x32_bf16(af[mi], bf0, acc[mi][0], 0, 0, 0);
      acc[mi][1] = __builtin_amdgcn_mfma_f32_16x16x32_bf16(af[mi], bf1, acc[mi][1], 0, 0, 0);
    }
    __builtin_amdgcn_s_setprio(0);
    __builtin_amdgcn_s_barrier();
    // ---- phase 1: n-frags 2,3
    bf0 = *(const short8*)(ra + 8192 + (wn * 64 + 32 + lm) * 64 + fo);
    bf1 = *(const short8*)(ra + 8192 + (wn * 64 + 48 + lm) * 64 + fo);
    if (stg) { gld16(pa, wb + wave * 2048); gld16(pa + 16 * S_, wb + wave * 2048 + 1024); pa += 32; pb += 32; }
    __builtin_amdgcn_s_barrier();
    __builtin_amdgcn_s_setprio(1);
#pragma unroll
    for (int mi = 0; mi < 4; mi++) {
      acc[mi][2] = __builtin_amdgcn_mfma_f32_16x16x32_bf16(af[mi], bf0, acc[mi][2], 0, 0, 0);
      acc[mi][3] = __builtin_amdgcn_mfma_f32_16x16x32_bf16(af[mi], bf1, acc[mi][3], 0, 0, 0);
    }
    __builtin_amdgcn_s_setprio(0);
    if (it < N - 1) {
      if (it + 2 < N) asm volatile("s_waitcnt vmcnt(4)" ::: "memory");
      else            asm volatile("s_waitcnt vmcnt(0)" ::: "memory");
    }
    __builtin_amdgcn_s_barrier();
    rbuf = (rbuf == 2) ? 0 : rbuf + 1;
  }
  for (int mi = 0; mi < 4; mi++) {
    for (int r = 0; r < 4; r++) {
      int q = q0 + wq * 64 + mi * 16 + lq * 4 + r;
      for (int ni = 0; ni < 4; ni++) {
        int n = n0 + wn * 64 + ni * 16 + lm;
        out[((size_t)(b * S_ + q)) * NO_ + n] = acc[mi][ni][r];
      }
    }
  }
}

// ---------------------------------------------------------------------------
extern "C" void kernel_launch(void* const* d_in, const int* in_sizes, int n_in,
                              void* d_out, int out_size, void* d_ws, size_t ws_size,
                              hipStream_t stream) {
  const float* H  = (const float*)d_in[0];   // [B,S,HID]
  const float* A  = (const float*)d_in[1];   // [B,S,S]
  const float* Wv = (const float*)d_in[3];   // [HID, NO]
  const float* bv = (const float*)d_in[4];   // [NO]
  float* out = (float*)d_out;

  char* ws = (char*)d_ws;
  ushort_t* WvT = (ushort_t*)ws;                                  //  2.0 MB
  ushort_t* Hb  = (ushort_t*)(ws + 2097152);                      // 16.8 MB
  ushort_t* Vt  = (ushort_t*)(ws + 2097152 + 16777216);           // 16.8 MB
  ushort_t* Abf = (ushort_t*)(ws + 2097152 + 2 * 16777216);       // 33.6 MB

  k_prep0<<<1024 + 8192, 256, 0, stream>>>(Wv, WvT, H, Hb);
  k_vtA  <<<512 + 2048, 256, 0, stream>>>(WvT, Hb, bv, Vt, A, Abf);
  k_attn <<<512, 256, 0, stream>>>(Abf, Vt, out);
}